// Round 4
// baseline (589.523 us; speedup 1.0000x reference)
//
#include <hip/hip_runtime.h>

#define DIM 4096
#define TOTAL 16384
#define STATE_LEN 3
#define BATCH 8
#define NSLOTS 256
#define TVEC (TOTAL / 4)                    // 4096 float4 per x row
#define F4PB 1024                           // float4 per conv block (256 thr × 4)
#define CONV_BLKS ((DIM * TVEC) / F4PB)     // 16384
#define SROW (DIM * STATE_LEN)              // 12288 floats per slot
#define S4_PER_SLOT (SROW / 4)              // 3072 float4 per slot
#define NSTATE4 (NSLOTS * S4_PER_SLOT)      // 786432 float4 of states
#define STATE_BLKS (NSTATE4 / 256)          // 3072

typedef float floatx4 __attribute__((ext_vector_type(4)));

// One-shot partitioned kernel.
//   blocks [0, CONV_BLKS)   : conv output — each thread 4 consecutive float4 (16 t)
//   blocks [CONV_BLKS, ...) : full out_states write (copy / recompute touched slots)
__global__ __launch_bounds__(256) void fused_kernel(
    const float* __restrict__ x, const float* __restrict__ weight,
    const float* __restrict__ cs, const int* __restrict__ qsl,
    const int* __restrict__ cache_indices, const int* __restrict__ init_mode,
    const int* __restrict__ pad_p, const int* __restrict__ res_p,
    float* __restrict__ out, float* __restrict__ out_states)
{
    if (blockIdx.x < CONV_BLKS) {
        // ---------------- conv part ----------------
        const int d   = blockIdx.x >> 2;                       // 4 blocks per row
        const int tvb = ((blockIdx.x & 3) << 10) | (threadIdx.x << 2);  // first float4 idx
        const int t0  = tvb << 2;                              // first t of this thread

        // 5 independent 16B loads issued up front (max MLP, same 4KB wave footprint)
        const floatx4* __restrict__ xr = (const floatx4*)x + (size_t)d * TVEC;
        floatx4 c0 = xr[tvb + 0];
        floatx4 c1 = xr[tvb + 1];
        floatx4 c2 = xr[tvb + 2];
        floatx4 c3 = xr[tvb + 3];
        floatx4 pv = xr[(tvb > 0) ? (tvb - 1) : 0];
        if (tvb == 0) pv = (floatx4){0.f, 0.f, 0.f, 0.f};

        int q[BATCH + 1];
        #pragma unroll
        for (int k = 0; k <= BATCH; k++) q[k] = qsl[k];        // wave-uniform

        floatx4 w = ((const floatx4*)weight)[d];               // uniform within block
        w.w += res_p[0] ? 1.0f : 0.0f;                         // fold residual into x[t] tap

        // win[3+j] = x[t0+j]; output j uses win[j..j+3]
        float win[19] = {pv.y, pv.z, pv.w,
                         c0.x, c0.y, c0.z, c0.w,
                         c1.x, c1.y, c1.z, c1.w,
                         c2.x, c2.y, c2.z, c2.w,
                         c3.x, c3.y, c3.z, c3.w};

        // one segment check for the whole 16-t tile (q sorted; rightmost match)
        int qs_lo = 0, qs_hi = 0;
        #pragma unroll
        for (int k = 1; k < BATCH; k++) {
            qs_lo = (t0      >= q[k]) ? q[k] : qs_lo;
            qs_hi = (t0 + 15 >= q[k]) ? q[k] : qs_hi;
        }

        float res[16];
        if ((qs_lo == qs_hi) && (t0 - qs_lo >= 3)) {
            // fast path (~98.5% of tiles): everything from x
            #pragma unroll
            for (int j = 0; j < 16; j++)
                res[j] = w.x * win[j] + w.y * win[j + 1] + w.z * win[j + 2] + w.w * win[j + 3];
        } else {
            const int pad = pad_p[0];
            int ci_[BATCH], im_[BATCH];
            #pragma unroll
            for (int k = 0; k < BATCH; k++) { ci_[k] = cache_indices[k]; im_[k] = init_mode[k]; }
            #pragma unroll
            for (int j = 0; j < 16; j++) {
                const int t = t0 + j;
                int qs = 0, civ = ci_[0], imv = im_[0];
                #pragma unroll
                for (int k = 1; k < BATCH; k++) {
                    bool m = (t >= q[k]);
                    qs  = m ? q[k]   : qs;
                    civ = m ? ci_[k] : civ;
                    imv = m ? im_[k] : imv;
                }
                const int p = t - qs;
                const float xt = win[3 + j];
                float acc;
                if (p >= 3) {
                    acc = w.x * win[j] + w.y * win[j + 1] + w.z * win[j + 2] + w.w * xt;
                } else {
                    bool valid = (civ != pad);
                    int slot = valid ? civ : 0;
                    bool use_init = valid && (imv != 0);
                    const float* csrow = cs + ((size_t)slot * DIM + d) * STATE_LEN;
                    float xm1 = (p >= 1) ? win[j + 2] : (use_init ? csrow[2 + p] : 0.f);
                    float xm2 = (p >= 2) ? win[j + 1] : (use_init ? csrow[1 + p] : 0.f);
                    float xm3 =                          (use_init ? csrow[0 + p] : 0.f);
                    acc = w.x * xm3 + w.y * xm2 + w.z * xm1 + w.w * xt;
                }
                res[j] = acc;
            }
        }

        floatx4* orow = (floatx4*)out + (size_t)d * TVEC;
        __builtin_nontemporal_store((floatx4){res[0],  res[1],  res[2],  res[3]},  orow + tvb + 0);
        __builtin_nontemporal_store((floatx4){res[4],  res[5],  res[6],  res[7]},  orow + tvb + 1);
        __builtin_nontemporal_store((floatx4){res[8],  res[9],  res[10], res[11]}, orow + tvb + 2);
        __builtin_nontemporal_store((floatx4){res[12], res[13], res[14], res[15]}, orow + tvb + 3);
    } else {
        // ---------------- states part ----------------
        const int f = (blockIdx.x - CONV_BLKS) * 256 + threadIdx.x;   // < NSTATE4 by grid sizing
        const int slot = f / S4_PER_SLOT;
        floatx4 cv = ((const floatx4*)cs)[f];                  // coalesced; common case = copy

        int q[BATCH + 1];
        #pragma unroll
        for (int k = 0; k <= BATCH; k++) q[k] = qsl[k];
        const int pad = pad_p[0];

        // slot -> batch lookup via select chain
        bool found = false; int start = 0, end = 0, imv = 0;
        #pragma unroll
        for (int k = 0; k < BATCH; k++) {
            int cik = cache_indices[k];
            bool m = (cik == slot) && (cik != pad);
            start = m ? q[k]     : start;
            end   = m ? q[k + 1] : end;
            imv   = m ? init_mode[k] : imv;
            found = found || m;
        }
        if (!found) {
            __builtin_nontemporal_store(cv, (floatx4*)out_states + f);
        } else {
            int L = end - start;
            bool init = (imv != 0);
            int base = (f - slot * S4_PER_SLOT) * 4;           // float index in slot (= d*3 + j)
            float r[4];
            #pragma unroll
            for (int e = 0; e < 4; e++) {
                int idx = base + e;
                int d = idx / 3;
                int j = idx - d * 3;
                int gx = end + j - STATE_LEN;
                float val;
                if (gx >= start) {
                    val = x[(size_t)d * TOTAL + gx];
                } else if (init) {
                    int sidx = L + j;                          // gx<start => L+j<3
                    if (sidx > STATE_LEN - 1) sidx = STATE_LEN - 1;
                    val = cs[(size_t)slot * SROW + d * STATE_LEN + sidx];
                } else {
                    val = 0.f;
                }
                r[e] = val;
            }
            __builtin_nontemporal_store((floatx4){r[0], r[1], r[2], r[3]},
                                        (floatx4*)out_states + f);
        }
    }
}

extern "C" void kernel_launch(void* const* d_in, const int* in_sizes, int n_in,
                              void* d_out, int out_size, void* d_ws, size_t ws_size,
                              hipStream_t stream) {
    const float* x      = (const float*)d_in[0];
    const float* weight = (const float*)d_in[1];
    const float* cs     = (const float*)d_in[2];
    const int*   qsl    = (const int*)d_in[3];
    const int*   ci     = (const int*)d_in[4];
    const int*   im     = (const int*)d_in[5];
    const int*   pad    = (const int*)d_in[6];
    const int*   res    = (const int*)d_in[7];

    float* out        = (float*)d_out;
    float* out_states = out + (size_t)DIM * TOTAL;

    fused_kernel<<<CONV_BLKS + STATE_BLKS, 256, 0, stream>>>(
        x, weight, cs, qsl, ci, im, pad, res, out, out_states);
}